// Round 1
// baseline (217.781 us; speedup 1.0000x reference)
//
#include <hip/hip_runtime.h>
#include <math.h>

// Problem constants (from reference)
#define BB 8192
#define DD 4096
#define EE 64
constexpr float NOISE_EPS = 0.01f;

constexpr int BM = 32;    // rows per block
constexpr int BN = 128;   // 64 clean logits + 64 noise logits
constexpr int BK = 32;    // K tile

__global__ __launch_bounds__(256) void noisy_topk_gating_kernel(
    const float* __restrict__ x,      // [B, D]
    const float* __restrict__ gw,     // [E, D]
    const float* __restrict__ ngw,    // [E, D]
    const float* __restrict__ noise,  // [B, E]
    float* __restrict__ out)          // gates [B,E] then load [B,E]
{
    __shared__ float xs[BK][BM + 4];   // k-major, padded (16B-aligned rows)
    __shared__ float ws[BK][BN + 4];   // k-major, padded
    __shared__ float lg[BM][BN + 2];   // logits for epilogue

    const int tid  = threadIdx.x;
    const int row0 = blockIdx.x * BM;

    const int tm = tid >> 5;        // 0..7
    const int tn = tid & 31;        // 0..31
    const int m0 = tm * 4;
    const int n0 = tn * 4;

    float acc[4][4] = {};

    // global-load assignments
    const int xr = tid >> 3;         // 0..31 (row within tile)
    const int xk = (tid & 7) * 4;    // 0,4,...,28

    // prefetch first tiles into registers
    float4 xv;
    float4 wv[4];
    int wn_[4], wk_[4];
    {
        xv = *reinterpret_cast<const float4*>(&x[(size_t)(row0 + xr) * DD + xk]);
        #pragma unroll
        for (int i = 0; i < 4; i++) {
            int idx = tid + i * 256;
            int wn  = idx >> 3;          // 0..127
            int wk  = (idx & 7) * 4;     // 0..28
            const float* wp = (wn < EE) ? &gw[(size_t)wn * DD]
                                        : &ngw[(size_t)(wn - EE) * DD];
            wv[i] = *reinterpret_cast<const float4*>(&wp[wk]);
            wn_[i] = wn; wk_[i] = wk;
        }
    }

    for (int k0 = 0; k0 < DD; k0 += BK) {
        __syncthreads();  // previous compute done reading LDS
        // regs -> LDS (transposed to k-major)
        xs[xk + 0][xr] = xv.x; xs[xk + 1][xr] = xv.y;
        xs[xk + 2][xr] = xv.z; xs[xk + 3][xr] = xv.w;
        #pragma unroll
        for (int i = 0; i < 4; i++) {
            ws[wk_[i] + 0][wn_[i]] = wv[i].x;
            ws[wk_[i] + 1][wn_[i]] = wv[i].y;
            ws[wk_[i] + 2][wn_[i]] = wv[i].z;
            ws[wk_[i] + 3][wn_[i]] = wv[i].w;
        }
        __syncthreads();

        // issue next-tile loads early: latency hides under compute below
        const int kn = k0 + BK;
        if (kn < DD) {
            xv = *reinterpret_cast<const float4*>(&x[(size_t)(row0 + xr) * DD + kn + xk]);
            #pragma unroll
            for (int i = 0; i < 4; i++) {
                const float* wp = (wn_[i] < EE) ? &gw[(size_t)wn_[i] * DD]
                                                : &ngw[(size_t)(wn_[i] - EE) * DD];
                wv[i] = *reinterpret_cast<const float4*>(&wp[kn + wk_[i]]);
            }
        }

        // compute on current tile
        #pragma unroll
        for (int k = 0; k < BK; k++) {
            const float4 a = *reinterpret_cast<const float4*>(&xs[k][m0]);
            const float4 b = *reinterpret_cast<const float4*>(&ws[k][n0]);
            acc[0][0] = fmaf(a.x, b.x, acc[0][0]);
            acc[0][1] = fmaf(a.x, b.y, acc[0][1]);
            acc[0][2] = fmaf(a.x, b.z, acc[0][2]);
            acc[0][3] = fmaf(a.x, b.w, acc[0][3]);
            acc[1][0] = fmaf(a.y, b.x, acc[1][0]);
            acc[1][1] = fmaf(a.y, b.y, acc[1][1]);
            acc[1][2] = fmaf(a.y, b.z, acc[1][2]);
            acc[1][3] = fmaf(a.y, b.w, acc[1][3]);
            acc[2][0] = fmaf(a.z, b.x, acc[2][0]);
            acc[2][1] = fmaf(a.z, b.y, acc[2][1]);
            acc[2][2] = fmaf(a.z, b.z, acc[2][2]);
            acc[2][3] = fmaf(a.z, b.w, acc[2][3]);
            acc[3][0] = fmaf(a.w, b.x, acc[3][0]);
            acc[3][1] = fmaf(a.w, b.y, acc[3][1]);
            acc[3][2] = fmaf(a.w, b.z, acc[3][2]);
            acc[3][3] = fmaf(a.w, b.w, acc[3][3]);
        }
    }

    // stash logits in LDS for the epilogue
    __syncthreads();
    #pragma unroll
    for (int i = 0; i < 4; i++)
        #pragma unroll
        for (int j = 0; j < 4; j++)
            lg[m0 + i][n0 + j] = acc[i][j];
    __syncthreads();

    // per-row epilogue: 32 rows handled by threads 0..31
    if (tid < BM) {
        const int r = tid;
        const size_t gb = (size_t)(row0 + r);

        float m1 = -3.4e38f, m2 = -3.4e38f;
        int   i1 = 0, i2 = 0;
        float cmax = -3.4e38f;
        #pragma unroll
        for (int e = 0; e < EE; e++) {
            float c  = lg[r][e];
            float nl = lg[r][EE + e];
            // softplus(nl), numerically stable
            float sp = fmaxf(nl, 0.0f) + log1pf(expf(-fabsf(nl)));
            float v  = c + noise[gb * EE + e] * sp * NOISE_EPS;
            if (v > m1)      { m2 = m1; i2 = i1; m1 = v; i1 = e; }
            else if (v > m2) { m2 = v;  i2 = e; }
            cmax = fmaxf(cmax, c);
        }
        // softmax over the two selected noisy logits
        float t  = expf(m2 - m1);
        float p1 = 1.0f / (1.0f + t);
        float p2 = t * p1;

        // clean-logit softmax (load): exp in place, then normalize
        float s = 0.0f;
        #pragma unroll
        for (int e = 0; e < EE; e++) {
            float ec = expf(lg[r][e] - cmax);
            s += ec;
            lg[r][e] = ec;
        }
        float inv = 1.0f / s;
        #pragma unroll
        for (int e = 0; e < EE; e++) {
            lg[r][e] *= inv;                                    // load row
            lg[r][EE + e] = (e == i1) ? p1 : ((e == i2) ? p2 : 0.0f); // gates row
        }
    }
    __syncthreads();

    // cooperative coalesced writes: gates then load
    #pragma unroll
    for (int i = 0; i < (BM * EE) / 256; i++) {
        int idx = tid + i * 256;
        int r   = idx >> 6;
        int e   = idx & 63;
        out[(size_t)(row0 + r) * EE + e] = lg[r][EE + e];                  // gates
        out[(size_t)BB * EE + (size_t)(row0 + r) * EE + e] = lg[r][e];     // load
    }
}

extern "C" void kernel_launch(void* const* d_in, const int* in_sizes, int n_in,
                              void* d_out, int out_size, void* d_ws, size_t ws_size,
                              hipStream_t stream) {
    const float* x     = (const float*)d_in[0];
    const float* gw    = (const float*)d_in[1];
    const float* ngw   = (const float*)d_in[2];
    const float* noise = (const float*)d_in[3];
    float* out = (float*)d_out;

    dim3 grid(BB / BM);   // 256 blocks
    dim3 block(256);
    hipLaunchKernelGGL(noisy_topk_gating_kernel, grid, block, 0, stream,
                       x, gw, ngw, noise, out);
}

// Round 3
// 162.783 us; speedup vs baseline: 1.3379x; 1.3379x over previous
//
#include <hip/hip_runtime.h>
#include <math.h>

#define BB 8192
#define DD 4096
#define EE 64

constexpr float NOISE_EPS = 0.01f;
constexpr int BM = 32;     // rows per block
constexpr int BN = 128;    // 64 clean + 64 noise logit columns
constexpr int BK = 32;     // K tile (one MFMA K-step)
constexpr int NT = DD / BK;

typedef __attribute__((ext_vector_type(8))) short bf16x8;
typedef __attribute__((ext_vector_type(4))) float f32x4;

// Plain row-major LDS layout: stride 32 bf16 = 64 B.
// Fragment reads (64 lanes x 16B) cover a contiguous 1024-B region -> bank-uniform.
__device__ __forceinline__ int LROW(int r) { return r * 64; }

constexpr int XPLANE = 32 * 64;    // 2048 B
constexpr int WPLANE = 128 * 64;   // 8192 B
// total LDS: 3*2048 + 3*8192 + 32*130*4 = 47360 B (< 64 KB)

struct Triple { unsigned h, m, l; };  // packed bf16 PAIRS (low short = lower k)

// 3-way bf16 split (truncation; residuals exact) of two floats,
// packed into one dword per level.
__device__ __forceinline__ Triple split_pair(float va, float vb) {
    unsigned ua = __float_as_uint(va), ub = __float_as_uint(vb);
    unsigned ha = ua & 0xFFFF0000u, hb = ub & 0xFFFF0000u;
    float ra = va - __uint_as_float(ha);
    float rb = vb - __uint_as_float(hb);
    unsigned uma = __float_as_uint(ra), umb = __float_as_uint(rb);
    unsigned ma = uma & 0xFFFF0000u, mb = umb & 0xFFFF0000u;
    float sa = ra - __uint_as_float(ma);
    float sb = rb - __uint_as_float(mb);
    unsigned ula = __float_as_uint(sa), ulb = __float_as_uint(sb);
    Triple t;
    t.h = (ua >> 16) | hb;
    t.m = (uma >> 16) | mb;
    t.l = (ula >> 16) | ulb;
    return t;
}

__global__ __launch_bounds__(512) void gating_mfma_kernel(
    const float* __restrict__ x,      // [B, D]
    const float* __restrict__ gw,     // [E, D]
    const float* __restrict__ ngw,    // [E, D]
    const float* __restrict__ noise,  // [B, E]
    float* __restrict__ out)          // gates [B,E] then load [B,E]
{
    __shared__ __align__(16) char xh[XPLANE], xm_[XPLANE], xl[XPLANE];
    __shared__ __align__(16) char wh[WPLANE], wm_[WPLANE], wl[WPLANE];
    __shared__ float lg[BM][BN + 2];

    const int tid  = threadIdx.x;
    const int row0 = blockIdx.x * BM;

    // staging assignments: x tile 32x32 (2 floats/thread), w tile 128x32 (8/thread)
    const int xr = tid >> 4;            // 0..31
    const int xc = (tid & 15) * 2;      // 0..30
    const int wr = tid >> 2;            // 0..127 (0-63 = gw, 64-127 = ngw)
    const int wc = (tid & 3) * 8;       // 0,8,16,24
    const float* xp = x + (size_t)(row0 + xr) * DD;
    const float* wp = (wr < EE) ? (gw + (size_t)wr * DD)
                                : (ngw + (size_t)(wr - EE) * DD);

    const int xwoff = LROW(xr) + xc * 2;     // byte offset for x-plane write (b32)
    const int wwoff = LROW(wr) + wc * 2;     // byte offset for w-plane write (b128)

    // wave / fragment assignments: 8 waves as 2M x 4N, wave tile 16x32
    const int lane = tid & 63;
    const int wv   = tid >> 6;
    const int wmi  = wv >> 2;           // 0..1  (m block of 16)
    const int wni  = wv & 3;            // 0..3  (n block of 32)
    const int l15  = lane & 15;
    const int kb   = (lane >> 4) * 16;  // k-group byte offset (8 bf16)
    const int aoff  = LROW(wmi * 16 + l15) + kb;
    const int b0off = LROW(wni * 32 + l15) + kb;
    const int b1off = LROW(wni * 32 + 16 + l15) + kb;

    f32x4 acc0 = {0.f, 0.f, 0.f, 0.f};
    f32x4 acc1 = {0.f, 0.f, 0.f, 0.f};

    // prologue: load tile 0 into registers
    float2 xv  = *reinterpret_cast<const float2*>(xp + xc);
    float4 wva = *reinterpret_cast<const float4*>(wp + wc);
    float4 wvb = *reinterpret_cast<const float4*>(wp + wc + 4);

    for (int t = 0; t < NT; ++t) {
        __syncthreads();   // previous iteration's fragment reads complete

        // ---- convert registers -> 3 bf16 planes in LDS ----
        {
            Triple tx = split_pair(xv.x, xv.y);
            *reinterpret_cast<unsigned*>(xh  + xwoff) = tx.h;
            *reinterpret_cast<unsigned*>(xm_ + xwoff) = tx.m;
            *reinterpret_cast<unsigned*>(xl  + xwoff) = tx.l;
            Triple t0 = split_pair(wva.x, wva.y);
            Triple t1 = split_pair(wva.z, wva.w);
            Triple t2 = split_pair(wvb.x, wvb.y);
            Triple t3 = split_pair(wvb.z, wvb.w);
            uint4 ph = {t0.h, t1.h, t2.h, t3.h};
            uint4 pm = {t0.m, t1.m, t2.m, t3.m};
            uint4 pl = {t0.l, t1.l, t2.l, t3.l};
            *reinterpret_cast<uint4*>(wh  + wwoff) = ph;
            *reinterpret_cast<uint4*>(wm_ + wwoff) = pm;
            *reinterpret_cast<uint4*>(wl  + wwoff) = pl;
        }
        __syncthreads();

        // ---- prefetch next tile into registers (in flight during MFMAs) ----
        if (t + 1 < NT) {
            const int k0 = (t + 1) * BK;
            xv  = *reinterpret_cast<const float2*>(xp + k0 + xc);
            wva = *reinterpret_cast<const float4*>(wp + k0 + wc);
            wvb = *reinterpret_cast<const float4*>(wp + k0 + wc + 4);
        }

        // ---- fragments + 12 MFMAs (6 split-products x 2 n-frags) ----
        bf16x8 ah = *reinterpret_cast<const bf16x8*>(xh  + aoff);
        bf16x8 am = *reinterpret_cast<const bf16x8*>(xm_ + aoff);
        bf16x8 al = *reinterpret_cast<const bf16x8*>(xl  + aoff);
        bf16x8 bh0 = *reinterpret_cast<const bf16x8*>(wh  + b0off);
        bf16x8 bm0 = *reinterpret_cast<const bf16x8*>(wm_ + b0off);
        bf16x8 bl0 = *reinterpret_cast<const bf16x8*>(wl  + b0off);
        bf16x8 bh1 = *reinterpret_cast<const bf16x8*>(wh  + b1off);
        bf16x8 bm1 = *reinterpret_cast<const bf16x8*>(wm_ + b1off);
        bf16x8 bl1 = *reinterpret_cast<const bf16x8*>(wl  + b1off);

        acc0 = __builtin_amdgcn_mfma_f32_16x16x32_bf16(ah, bh0, acc0, 0, 0, 0);
        acc1 = __builtin_amdgcn_mfma_f32_16x16x32_bf16(ah, bh1, acc1, 0, 0, 0);
        acc0 = __builtin_amdgcn_mfma_f32_16x16x32_bf16(ah, bm0, acc0, 0, 0, 0);
        acc1 = __builtin_amdgcn_mfma_f32_16x16x32_bf16(ah, bm1, acc1, 0, 0, 0);
        acc0 = __builtin_amdgcn_mfma_f32_16x16x32_bf16(am, bh0, acc0, 0, 0, 0);
        acc1 = __builtin_amdgcn_mfma_f32_16x16x32_bf16(am, bh1, acc1, 0, 0, 0);
        acc0 = __builtin_amdgcn_mfma_f32_16x16x32_bf16(ah, bl0, acc0, 0, 0, 0);
        acc1 = __builtin_amdgcn_mfma_f32_16x16x32_bf16(ah, bl1, acc1, 0, 0, 0);
        acc0 = __builtin_amdgcn_mfma_f32_16x16x32_bf16(am, bm0, acc0, 0, 0, 0);
        acc1 = __builtin_amdgcn_mfma_f32_16x16x32_bf16(am, bm1, acc1, 0, 0, 0);
        acc0 = __builtin_amdgcn_mfma_f32_16x16x32_bf16(al, bh0, acc0, 0, 0, 0);
        acc1 = __builtin_amdgcn_mfma_f32_16x16x32_bf16(al, bh1, acc1, 0, 0, 0);
    }

    // ---- accumulators -> logits LDS tile ----
    {
        const int rbase = wmi * 16 + (lane >> 4) * 4;
        const int c0 = wni * 32 + l15;
        #pragma unroll
        for (int j = 0; j < 4; j++) {
            lg[rbase + j][c0]      = acc0[j];
            lg[rbase + j][c0 + 16] = acc1[j];
        }
    }
    __syncthreads();

    // ---- per-row epilogue (threads 0..31) ----
    if (tid < BM) {
        const int r = tid;
        const size_t gb = (size_t)(row0 + r);

        float m1 = -3.4e38f, m2 = -3.4e38f;
        int   i1 = 0, i2 = 0;
        float cmax = -3.4e38f;
        #pragma unroll
        for (int e = 0; e < EE; e++) {
            float c  = lg[r][e];
            float nl = lg[r][EE + e];
            float sp = fmaxf(nl, 0.0f) + log1pf(expf(-fabsf(nl)));  // softplus
            float v  = c + noise[gb * EE + e] * sp * NOISE_EPS;
            if (v > m1)      { m2 = m1; i2 = i1; m1 = v; i1 = e; }
            else if (v > m2) { m2 = v;  i2 = e; }
            cmax = fmaxf(cmax, c);
        }
        float tq  = expf(m2 - m1);
        float p1 = 1.0f / (1.0f + tq);
        float p2 = tq * p1;

        float s = 0.0f;
        #pragma unroll
        for (int e = 0; e < EE; e++) {
            float ec = expf(lg[r][e] - cmax);
            s += ec;
            lg[r][e] = ec;
        }
        float inv = 1.0f / s;
        #pragma unroll
        for (int e = 0; e < EE; e++) {
            lg[r][e] *= inv;                                             // load
            lg[r][EE + e] = (e == i1) ? p1 : ((e == i2) ? p2 : 0.0f);    // gates
        }
    }
    __syncthreads();

    // ---- coalesced output writes: gates then load ----
    #pragma unroll
    for (int i = 0; i < (BM * EE) / 512; i++) {
        int idx = tid + i * 512;
        int r   = idx >> 6;
        int e   = idx & 63;
        out[(size_t)(row0 + r) * EE + e] = lg[r][EE + e];                 // gates
        out[(size_t)BB * EE + (size_t)(row0 + r) * EE + e] = lg[r][e];    // load
    }
}

extern "C" void kernel_launch(void* const* d_in, const int* in_sizes, int n_in,
                              void* d_out, int out_size, void* d_ws, size_t ws_size,
                              hipStream_t stream) {
    const float* x     = (const float*)d_in[0];
    const float* gw    = (const float*)d_in[1];
    const float* ngw   = (const float*)d_in[2];
    const float* noise = (const float*)d_in[3];
    float* out = (float*)d_out;

    dim3 grid(BB / BM);   // 256 blocks
    dim3 block(512);
    hipLaunchKernelGGL(gating_mfma_kernel, grid, block, 0, stream,
                       x, gw, ngw, noise, out);
}

// Round 4
// 77.724 us; speedup vs baseline: 2.8020x; 2.0944x over previous
//
#include <hip/hip_runtime.h>
#include <math.h>

#define BB 8192
#define DD 4096
#define EE 64

constexpr float NOISE_EPS = 0.01f;
constexpr int BM = 32;              // rows per block
constexpr int BK = 32;              // K per pipeline stage (one MFMA K)
constexpr int NT = DD / BK;         // 128

typedef __attribute__((ext_vector_type(8))) _Float16 f16x8;
typedef __attribute__((ext_vector_type(2))) _Float16 f16x2;
typedef __attribute__((ext_vector_type(4))) float    f32x4;

// fp32 = hi + mid + r, |r| <= 2^-24 |v|  (two RN fp16 levels)
// kept products: (xh+xm)(wh+wm)  -> operand-level error ~2^-24, fp32-class.

__global__ __launch_bounds__(512) void gating_f16_kernel(
    const float* __restrict__ x,      // [B, D]
    const float* __restrict__ gw,     // [E, D]
    const float* __restrict__ ngw,    // [E, D]
    const float* __restrict__ noise,  // [B, E]
    float* __restrict__ out)          // gates [B,E] then load [B,E]
{
    // [buf][plane][row*BK + k], linear rows of 64 B -> contiguous wave b128 reads
    __shared__ __align__(16) _Float16 xpl[2][2][BM * BK];    //  8 KB
    __shared__ __align__(16) _Float16 wpl[2][2][128 * BK];   // 32 KB
    __shared__ float lg[BM][132];                            // ~16.9 KB

    const int tid  = threadIdx.x;
    const int row0 = blockIdx.x * BM;

    // ---- staging assignments ----
    const int xr = tid >> 4;            // 0..31
    const int xc = (tid & 15) * 2;      // 0..30  (2 floats/thread)
    const int wr = tid >> 2;            // 0..127 (0-63 gw, 64-127 ngw)
    const int wc = (tid & 3) * 8;       // 0,8,16,24 (8 floats/thread)
    const float* xp = x + (size_t)(row0 + xr) * DD + xc;
    const float* wp = ((wr < EE) ? (gw + (size_t)wr * DD)
                                 : (ngw + (size_t)(wr - EE) * DD)) + wc;
    const int xso = xr * BK + xc;       // halfword index in x plane
    const int wso = wr * BK + wc;       // halfword index in w plane

    // ---- wave / fragment assignments: 8 waves = 2M x 4N, wave tile 16x32 ----
    const int lane = tid & 63;
    const int wv   = tid >> 6;
    const int wmi  = wv >> 2;           // 0..1
    const int wni  = wv & 3;            // 0..3
    const int l15  = lane & 15;
    const int kq   = lane >> 4;         // k-group (8 halves)
    const int aoff  = (wmi * 16 + l15) * BK + kq * 8;
    const int b0off = (wni * 32 + l15) * BK + kq * 8;
    const int b1off = b0off + 16 * BK;

    f32x4 acc0 = {0.f, 0.f, 0.f, 0.f};
    f32x4 acc1 = {0.f, 0.f, 0.f, 0.f};

    // ---- prologue: tile 0 -> buf 0; start x prefetch chain ----
    float4 w0 = *reinterpret_cast<const float4*>(wp);
    float4 w1 = *reinterpret_cast<const float4*>(wp + 4);
    float2 xa = *reinterpret_cast<const float2*>(xp);
    {
        float v[8] = {w0.x, w0.y, w0.z, w0.w, w1.x, w1.y, w1.z, w1.w};
        f16x8 hi, mi;
        #pragma unroll
        for (int j = 0; j < 8; ++j) {
            _Float16 h = (_Float16)v[j];
            hi[j] = h;
            mi[j] = (_Float16)(v[j] - (float)h);
        }
        *reinterpret_cast<f16x8*>(&wpl[0][0][wso]) = hi;
        *reinterpret_cast<f16x8*>(&wpl[0][1][wso]) = mi;

        _Float16 h0 = (_Float16)xa.x, h1 = (_Float16)xa.y;
        f16x2 xhi = {h0, h1};
        f16x2 xmi = {(_Float16)(xa.x - (float)h0), (_Float16)(xa.y - (float)h1)};
        *reinterpret_cast<f16x2*>(&xpl[0][0][xso]) = xhi;
        *reinterpret_cast<f16x2*>(&xpl[0][1][xso]) = xmi;
    }
    xa = *reinterpret_cast<const float2*>(xp + BK);   // tile 1 in regs
    __syncthreads();

    float2 xb = {0.f, 0.f};

    // ---- main loop: 1 barrier per iter, double-buffered ----
    for (int t = 0; t < NT; ++t) {
        const int cur = t & 1, nxt = cur ^ 1;

        // issue next-tile global loads first (latency hides under frag+MFMA)
        if (t + 1 < NT) {
            const int k1 = (t + 1) * BK;
            w0 = *reinterpret_cast<const float4*>(wp + k1);
            w1 = *reinterpret_cast<const float4*>(wp + k1 + 4);
        }
        if (t + 2 < NT) {
            xb = *reinterpret_cast<const float2*>(xp + (t + 2) * BK);
        }

        // fragments from current buffer
        f16x8 ah  = *reinterpret_cast<const f16x8*>(&xpl[cur][0][aoff]);
        f16x8 am  = *reinterpret_cast<const f16x8*>(&xpl[cur][1][aoff]);
        f16x8 b0h = *reinterpret_cast<const f16x8*>(&wpl[cur][0][b0off]);
        f16x8 b0m = *reinterpret_cast<const f16x8*>(&wpl[cur][1][b0off]);
        f16x8 b1h = *reinterpret_cast<const f16x8*>(&wpl[cur][0][b1off]);
        f16x8 b1m = *reinterpret_cast<const f16x8*>(&wpl[cur][1][b1off]);

        acc0 = __builtin_amdgcn_mfma_f32_16x16x32_f16(ah, b0h, acc0, 0, 0, 0);
        acc1 = __builtin_amdgcn_mfma_f32_16x16x32_f16(ah, b1h, acc1, 0, 0, 0);
        acc0 = __builtin_amdgcn_mfma_f32_16x16x32_f16(am, b0h, acc0, 0, 0, 0);
        acc1 = __builtin_amdgcn_mfma_f32_16x16x32_f16(am, b1h, acc1, 0, 0, 0);
        acc0 = __builtin_amdgcn_mfma_f32_16x16x32_f16(ah, b0m, acc0, 0, 0, 0);
        acc1 = __builtin_amdgcn_mfma_f32_16x16x32_f16(ah, b1m, acc1, 0, 0, 0);
        acc0 = __builtin_amdgcn_mfma_f32_16x16x32_f16(am, b0m, acc0, 0, 0, 0);
        acc1 = __builtin_amdgcn_mfma_f32_16x16x32_f16(am, b1m, acc1, 0, 0, 0);

        // stage tile t+1 into the other buffer
        if (t + 1 < NT) {
            float v[8] = {w0.x, w0.y, w0.z, w0.w, w1.x, w1.y, w1.z, w1.w};
            f16x8 hi, mi;
            #pragma unroll
            for (int j = 0; j < 8; ++j) {
                _Float16 h = (_Float16)v[j];
                hi[j] = h;
                mi[j] = (_Float16)(v[j] - (float)h);
            }
            *reinterpret_cast<f16x8*>(&wpl[nxt][0][wso]) = hi;
            *reinterpret_cast<f16x8*>(&wpl[nxt][1][wso]) = mi;

            _Float16 h0 = (_Float16)xa.x, h1 = (_Float16)xa.y;
            f16x2 xhi = {h0, h1};
            f16x2 xmi = {(_Float16)(xa.x - (float)h0), (_Float16)(xa.y - (float)h1)};
            *reinterpret_cast<f16x2*>(&xpl[nxt][0][xso]) = xhi;
            *reinterpret_cast<f16x2*>(&xpl[nxt][1][xso]) = xmi;

            xa = xb;
        }
        __syncthreads();
    }

    // ---- accumulators -> logits tile ----
    {
        const int rb = wmi * 16 + kq * 4;
        const int c0 = wni * 32 + l15;
        #pragma unroll
        for (int j = 0; j < 4; ++j) {
            lg[rb + j][c0]      = acc0[j];
            lg[rb + j][c0 + 16] = acc1[j];
        }
    }
    __syncthreads();

    // ---- parallel epilogue: wave wv owns rows 4wv..4wv+3; 16 lanes/row ----
    {
        const int r    = wv * 4 + kq;        // row in tile
        const int s    = l15;                // 16-lane slot; experts 4s..4s+3
        const int grow = row0 + r;

        float4 nz = *reinterpret_cast<const float4*>(noise + (size_t)grow * EE + 4 * s);

        float cc[4];
        float m1 = -3.4e38f, m2 = -3.4e38f;
        int   i1 = -1, i2 = -1;
        float cmax = -3.4e38f;
        #pragma unroll
        for (int j = 0; j < 4; ++j) {
            const int e = 4 * s + j;
            float c  = lg[r][e];
            float nl = lg[r][EE + e];
            cc[j] = c;
            float sp  = fmaxf(nl, 0.0f) + log1pf(expf(-fabsf(nl)));  // softplus
            float nzj = (j == 0) ? nz.x : (j == 1) ? nz.y : (j == 2) ? nz.z : nz.w;
            float vno = fmaf(nzj * sp, NOISE_EPS, c);
            if (vno > m1)      { m2 = m1; i2 = i1; m1 = vno; i1 = e; }
            else if (vno > m2) { m2 = vno; i2 = e; }
            cmax = fmaxf(cmax, c);
        }

        // reduce across the 16-lane group: top-2 (value, lower-index tiebreak) + max
        #pragma unroll
        for (int m = 1; m < 16; m <<= 1) {
            float b1 = __shfl_xor(m1, m, 16);
            int  bi1 = __shfl_xor(i1, m, 16);
            float b2 = __shfl_xor(m2, m, 16);
            int  bi2 = __shfl_xor(i2, m, 16);
            float o  = __shfl_xor(cmax, m, 16);
            cmax = fmaxf(cmax, o);

            bool bwin = (b1 > m1) || (b1 == m1 && bi1 < i1);
            float t1; int ti1; float t2; int ti2;
            if (bwin) {
                t1 = b1; ti1 = bi1;
                bool aw = (m1 > b2) || (m1 == b2 && i1 < bi2);
                t2 = aw ? m1 : b2; ti2 = aw ? i1 : bi2;
            } else {
                t1 = m1; ti1 = i1;
                bool bw = (b1 > m2) || (b1 == m2 && bi1 < i2);
                t2 = bw ? b1 : m2; ti2 = bw ? bi1 : i2;
            }
            m1 = t1; i1 = ti1; m2 = t2; i2 = ti2;
        }

        float tq = expf(m2 - m1);
        float p1 = 1.0f / (1.0f + tq);
        float p2 = tq * p1;

        float e0 = expf(cc[0] - cmax);
        float e1 = expf(cc[1] - cmax);
        float e2 = expf(cc[2] - cmax);
        float e3 = expf(cc[3] - cmax);
        float sum = e0 + e1 + e2 + e3;
        #pragma unroll
        for (int m = 1; m < 16; m <<= 1) sum += __shfl_xor(sum, m, 16);
        float inv = 1.0f / sum;

        const int eb = 4 * s;
        float4 gt;
        gt.x = (eb     == i1) ? p1 : (eb     == i2) ? p2 : 0.0f;
        gt.y = (eb + 1 == i1) ? p1 : (eb + 1 == i2) ? p2 : 0.0f;
        gt.z = (eb + 2 == i1) ? p1 : (eb + 2 == i2) ? p2 : 0.0f;
        gt.w = (eb + 3 == i1) ? p1 : (eb + 3 == i2) ? p2 : 0.0f;
        float4 ld = {e0 * inv, e1 * inv, e2 * inv, e3 * inv};

        *reinterpret_cast<float4*>(out + (size_t)grow * EE + eb) = gt;
        *reinterpret_cast<float4*>(out + (size_t)BB * EE + (size_t)grow * EE + eb) = ld;
    }
}

extern "C" void kernel_launch(void* const* d_in, const int* in_sizes, int n_in,
                              void* d_out, int out_size, void* d_ws, size_t ws_size,
                              hipStream_t stream) {
    const float* x     = (const float*)d_in[0];
    const float* gw    = (const float*)d_in[1];
    const float* ngw   = (const float*)d_in[2];
    const float* noise = (const float*)d_in[3];
    float* out = (float*)d_out;

    dim3 grid(BB / BM);   // 256 blocks
    dim3 block(512);
    hipLaunchKernelGGL(gating_f16_kernel, grid, block, 0, stream,
                       x, gw, ngw, noise, out);
}